// Round 1
// baseline (6878.583 us; speedup 1.0000x reference)
//
#include <hip/hip_runtime.h>

#define LOG2E 1.4426950408889634f

struct __align__(8) PK { float c2; unsigned aw; };

__device__ __forceinline__ unsigned short f2bf(float f) {
  unsigned u = __float_as_uint(f);
  u += 0x7FFFu + ((u >> 16) & 1u);            // round-to-nearest-even
  return (unsigned short)(u >> 16);
}
__device__ __forceinline__ unsigned pk2(float a, float b) {
  return (unsigned)f2bf(a) | ((unsigned)f2bf(b) << 16);
}
__device__ __forceinline__ float bl16(unsigned u) { return __uint_as_float(u << 16); }
__device__ __forceinline__ float bh16(unsigned u) { return __uint_as_float(u & 0xFFFF0000u); }

// sigmoid-weighted accumulate: t = c2 - a2*vi = log2e*sigma*(mu - vi)
// e = 2^t = exp(-sigma*(vi-mu)); sig = 1/(1+e); an += we*sig; ad += |we|*sig
__device__ __forceinline__ void sigacc(PK p, float vi, float& an, float& ad) {
  float a2 = bl16(p.aw);
  float we = bh16(p.aw);
  float t  = fmaf(-a2, vi, p.c2);
  float e  = __builtin_amdgcn_exp2f(t);
  float r  = __builtin_amdgcn_rcpf(1.0f + e);
  an = fmaf(we, r, an);
  ad = fmaf(fabsf(we), r, ad);
}

// ---------------- prep: fold constants, softplus, pack params ----------------
__global__ __launch_bounds__(256) void prep_kernel(
    const float* __restrict__ sigma, const float* __restrict__ mu,
    const float* __restrict__ w,     const float* __restrict__ erev,
    const float* __restrict__ ss,    const float* __restrict__ smu,
    const float* __restrict__ sw,    const float* __restrict__ serev,
    const float* __restrict__ iw,    const float* __restrict__ ib,
    const float* __restrict__ gleak, const float* __restrict__ vleak,
    const float* __restrict__ cm,
    PK* __restrict__ Prec, PK* __restrict__ Psen, float* __restrict__ vecs)
{
  int gid = blockIdx.x * 256 + threadIdx.x;
  if (gid < 16384) {
    float a2 = sigma[gid] * LOG2E;
    float c2 = a2 * mu[gid];
    float sp = log1pf(expf(w[gid]));          // softplus(w)
    float we = sp * erev[gid];                // erev = +-1
    PK p; p.c2 = c2; p.aw = pk2(a2, we);
    Prec[gid] = p;
  } else if (gid < 32768) {
    int e = gid - 16384;
    int i = e >> 7;                           // sensory row (D dim)
    float a2 = ss[e] * iw[i] * LOG2E;         // fold input_w
    float c2 = ss[e] * (smu[e] - ib[i]) * LOG2E; // fold input_b
    float sp = log1pf(expf(sw[e]));
    float we = sp * serev[e];
    PK p; p.c2 = c2; p.aw = pk2(a2, we);
    Psen[e] = p;
  } else if (gid < 32896) {
    int jj = gid - 32768;
    float gp = log1pf(expf(gleak[jj]));
    vecs[jj]       = log1pf(expf(cm[jj])) * 4.0f; // cm_t = softplus(cm)*ODE_UNFOLDS
    vecs[128 + jj] = gp;                          // gleak_p
    vecs[256 + jj] = gp * vleak[jj];              // gleak_p * vleak
  }
}

// ---------------- stage A: h = LN(x @ W^T + b), write bf16 ----------------
__global__ __launch_bounds__(256) void stage_a(
    const float* __restrict__ x, const float* __restrict__ W,
    const float* __restrict__ pb, const float* __restrict__ lg,
    const float* __restrict__ lb, uint4* __restrict__ hout)
{
  extern __shared__ char smem[];
  float* Wt = (float*)smem;            // [128][132] transposed W (k-major), padded
  float* xs = Wt + 128 * 132;          // [32][132]
  const int tid = threadIdx.x;

  // load W[j][k] -> Wt[k][j] (transpose; pad 132 breaks write bank conflicts)
  #pragma unroll
  for (int ii = 0; ii < 16; ++ii) {
    int f = tid + (ii << 8);
    int jrow = f >> 5, kq = f & 31;
    float4 wv = ((const float4*)W)[f];
    float* wd = Wt + jrow;
    wd[(4 * kq + 0) * 132] = wv.x;
    wd[(4 * kq + 1) * 132] = wv.y;
    wd[(4 * kq + 2) * 132] = wv.z;
    wd[(4 * kq + 3) * 132] = wv.w;
  }
  const size_t R0 = (size_t)blockIdx.x << 5;   // 32 rows per block
  const float4* xg = (const float4*)(x + (R0 << 7));
  #pragma unroll
  for (int ii = 0; ii < 4; ++ii) {
    int f = tid + (ii << 8);
    int r = f >> 5, kq = f & 31;
    *(float4*)(xs + r * 132 + (kq << 2)) = xg[f];
  }
  __syncthreads();

  const int tr = tid >> 4, tc = tid & 15;
  const int r0 = tr << 1, j0 = tc << 3;
  float a0[8], a1[8];
  #pragma unroll
  for (int c = 0; c < 8; ++c) { a0[c] = 0.f; a1[c] = 0.f; }
  const float* xr0 = xs + r0 * 132;
  const float* xr1 = xs + (r0 + 1) * 132;
  const float* wc = Wt + j0;
  for (int k = 0; k < 128; k += 4) {
    float4 xa = *(const float4*)(xr0 + k);
    float4 xb = *(const float4*)(xr1 + k);
    #pragma unroll
    for (int s = 0; s < 4; ++s) {
      float4 w0 = *(const float4*)(wc + (k + s) * 132);
      float4 w1 = *(const float4*)(wc + (k + s) * 132 + 4);
      float xav = s == 0 ? xa.x : s == 1 ? xa.y : s == 2 ? xa.z : xa.w;
      float xbv = s == 0 ? xb.x : s == 1 ? xb.y : s == 2 ? xb.z : xb.w;
      a0[0] = fmaf(xav, w0.x, a0[0]); a0[1] = fmaf(xav, w0.y, a0[1]);
      a0[2] = fmaf(xav, w0.z, a0[2]); a0[3] = fmaf(xav, w0.w, a0[3]);
      a0[4] = fmaf(xav, w1.x, a0[4]); a0[5] = fmaf(xav, w1.y, a0[5]);
      a0[6] = fmaf(xav, w1.z, a0[6]); a0[7] = fmaf(xav, w1.w, a0[7]);
      a1[0] = fmaf(xbv, w0.x, a1[0]); a1[1] = fmaf(xbv, w0.y, a1[1]);
      a1[2] = fmaf(xbv, w0.z, a1[2]); a1[3] = fmaf(xbv, w0.w, a1[3]);
      a1[4] = fmaf(xbv, w1.x, a1[4]); a1[5] = fmaf(xbv, w1.y, a1[5]);
      a1[6] = fmaf(xbv, w1.z, a1[6]); a1[7] = fmaf(xbv, w1.w, a1[7]);
    }
  }
  // bias
  float4 pb0 = *(const float4*)(pb + j0);
  float4 pb1 = *(const float4*)(pb + j0 + 4);
  a0[0] += pb0.x; a0[1] += pb0.y; a0[2] += pb0.z; a0[3] += pb0.w;
  a0[4] += pb1.x; a0[5] += pb1.y; a0[6] += pb1.z; a0[7] += pb1.w;
  a1[0] += pb0.x; a1[1] += pb0.y; a1[2] += pb0.z; a1[3] += pb0.w;
  a1[4] += pb1.x; a1[5] += pb1.y; a1[6] += pb1.z; a1[7] += pb1.w;
  // per-row LN via 16-lane shuffle reduce (rows live in 16 consecutive lanes)
  float s0 = 0, q0 = 0, s1 = 0, q1 = 0;
  #pragma unroll
  for (int c = 0; c < 8; ++c) {
    s0 += a0[c]; q0 = fmaf(a0[c], a0[c], q0);
    s1 += a1[c]; q1 = fmaf(a1[c], a1[c], q1);
  }
  #pragma unroll
  for (int m = 1; m < 16; m <<= 1) {
    s0 += __shfl_xor(s0, m, 64); q0 += __shfl_xor(q0, m, 64);
    s1 += __shfl_xor(s1, m, 64); q1 += __shfl_xor(q1, m, 64);
  }
  float mu0 = s0 * (1.f / 128.f), mu1 = s1 * (1.f / 128.f);
  float rs0 = rsqrtf(fmaf(-mu0, mu0, q0 * (1.f / 128.f)) + 1e-5f);
  float rs1 = rsqrtf(fmaf(-mu1, mu1, q1 * (1.f / 128.f)) + 1e-5f);
  float4 g0 = *(const float4*)(lg + j0), g1 = *(const float4*)(lg + j0 + 4);
  float4 b0 = *(const float4*)(lb + j0), b1 = *(const float4*)(lb + j0 + 4);
  float n0[8], n1[8];
  const float* gv = (const float*)&g0; const float* bv = (const float*)&b0;
  #pragma unroll
  for (int c = 0; c < 4; ++c) {
    n0[c] = fmaf((a0[c] - mu0) * rs0, gv[c], bv[c]);
    n1[c] = fmaf((a1[c] - mu1) * rs1, gv[c], bv[c]);
  }
  const float* gv1 = (const float*)&g1; const float* bv1 = (const float*)&b1;
  #pragma unroll
  for (int c = 0; c < 4; ++c) {
    n0[4 + c] = fmaf((a0[4 + c] - mu0) * rs0, gv1[c], bv1[c]);
    n1[4 + c] = fmaf((a1[4 + c] - mu1) * rs1, gv1[c], bv1[c]);
  }
  uint4 o0, o1;
  o0.x = pk2(n0[0], n0[1]); o0.y = pk2(n0[2], n0[3]);
  o0.z = pk2(n0[4], n0[5]); o0.w = pk2(n0[6], n0[7]);
  o1.x = pk2(n1[0], n1[1]); o1.y = pk2(n1[2], n1[3]);
  o1.z = pk2(n1[4], n1[5]); o1.w = pk2(n1[6], n1[7]);
  hout[(R0 + r0) * 16 + tc] = o0;
  hout[(R0 + r0 + 1) * 16 + tc] = o1;
}

// ---------------- stage B: sensory terms for all (b,t) ----------------
__global__ __launch_bounds__(512) void sensory_kernel(
    const PK* __restrict__ Pg, const uint4* __restrict__ hbf,
    unsigned* __restrict__ ndg)
{
  extern __shared__ char smem[];
  PK* Pk      = (PK*)smem;                 // 131072 B
  float* hr   = (float*)(smem + 131072);   // 512 B
  float2* pnd = (float2*)(smem + 131584);  // 4096 B
  const int tid = threadIdx.x;

  #pragma unroll
  for (int k = 0; k < 32; ++k) { int idx = tid + (k << 9); Pk[idx] = Pg[idx]; }

  const int w = tid >> 6, l = tid & 63;
  const int j = ((w & 1) << 6) | l;   // output unit
  const int g = w >> 1;               // i-quarter
  const int i0 = g << 5;
  const PK* prow = Pk + i0 * 128 + j;
  const float* hbase = hr + i0;
  const int p0 = blockIdx.x << 9;     // 512 pairs per block

  for (int q = 0; q < 512; ++q) {
    const int p = p0 + q;
    if (tid < 16) {
      uint4 hh = hbf[(size_t)p * 16 + tid];
      float* d = hr + (tid << 3);
      d[0] = bl16(hh.x); d[1] = bh16(hh.x);
      d[2] = bl16(hh.y); d[3] = bh16(hh.y);
      d[4] = bl16(hh.z); d[5] = bh16(hh.z);
      d[6] = bl16(hh.w); d[7] = bh16(hh.w);
    }
    __syncthreads();
    float an0 = 0.f, ad0 = 0.f, an1 = 0.f, ad1 = 0.f;
    #pragma unroll
    for (int k = 0; k < 32; k += 4) {
      float4 vv = *(const float4*)(hbase + k);
      sigacc(prow[(k + 0) * 128], vv.x, an0, ad0);
      sigacc(prow[(k + 1) * 128], vv.y, an1, ad1);
      sigacc(prow[(k + 2) * 128], vv.z, an0, ad0);
      sigacc(prow[(k + 3) * 128], vv.w, an1, ad1);
    }
    pnd[(g << 7) + j] = make_float2(an0 + an1, ad0 + ad1);
    __syncthreads();
    if (tid < 128) {
      float2 s0 = pnd[tid], s1 = pnd[128 + tid], s2 = pnd[256 + tid], s3 = pnd[384 + tid];
      float num = s0.x + s1.x + s2.x + s3.x;
      float den = s0.y + s1.y + s2.y + s3.y;
      ndg[(size_t)p * 128 + tid] = pk2(num, den);
    }
  }
}

// ---------------- stage C: the sequential LTC scan, one block per batch ----------------
__global__ __launch_bounds__(512) void ltc_scan(
    const PK* __restrict__ Pg, const float* __restrict__ vecs,
    const unsigned* __restrict__ ndg,
    const float* __restrict__ ow, const float* __restrict__ ob,
    const float* __restrict__ lng, const float* __restrict__ lnb,
    const float* __restrict__ hW, const float* __restrict__ hb,
    float* __restrict__ out)
{
  extern __shared__ char smem[];
  PK* Pk        = (PK*)smem;                  // 131072
  float* v      = (float*)(smem + 131072);    // 512
  float2* pnd   = (float2*)(smem + 131584);   // 4096
  unsigned* ndc = (unsigned*)(smem + 135680); // 512
  float* cmt    = (float*)(smem + 136192);    // 512
  float* gd     = (float*)(smem + 136704);    // 512
  float* gn     = (float*)(smem + 137216);    // 512

  const int tid = threadIdx.x;
  const int b = blockIdx.x;

  #pragma unroll
  for (int k = 0; k < 32; ++k) { int idx = tid + (k << 9); Pk[idx] = Pg[idx]; }
  if (tid < 128) {
    cmt[tid] = vecs[tid];
    gd[tid]  = vecs[128 + tid];
    gn[tid]  = vecs[256 + tid];
    v[tid]   = 0.f;
  }
  __syncthreads();

  const int w = tid >> 6, l = tid & 63;
  const int j = ((w & 1) << 6) | l;
  const int g = w >> 1;
  const int i0 = g << 5;
  const PK* prow = Pk + i0 * 128 + j;
  const float* vbase = v + i0;
  const size_t ndbase = (size_t)b * 1024 * 128;

  for (int t = 0; t < 1024; ++t) {
    if (tid >= 128 && tid < 256)
      ndc[tid - 128] = ndg[ndbase + ((size_t)t << 7) + (tid - 128)];
    for (int u = 0; u < 4; ++u) {
      float an0 = 0.f, ad0 = 0.f, an1 = 0.f, ad1 = 0.f;
      #pragma unroll
      for (int k = 0; k < 32; k += 4) {
        float4 vv = *(const float4*)(vbase + k);
        sigacc(prow[(k + 0) * 128], vv.x, an0, ad0);
        sigacc(prow[(k + 1) * 128], vv.y, an1, ad1);
        sigacc(prow[(k + 2) * 128], vv.z, an0, ad0);
        sigacc(prow[(k + 3) * 128], vv.w, an1, ad1);
      }
      pnd[(g << 7) + j] = make_float2(an0 + an1, ad0 + ad1);
      __syncthreads();
      if (tid < 128) {
        float2 s0 = pnd[tid], s1 = pnd[128 + tid], s2 = pnd[256 + tid], s3 = pnd[384 + tid];
        unsigned nd = ndc[tid];
        float num = s0.x + s1.x + s2.x + s3.x + bl16(nd);
        float den = s0.y + s1.y + s2.y + s3.y + bh16(nd);
        float vj = v[tid];
        v[tid] = (fmaf(cmt[tid], vj, gn[tid]) + num) /
                 (cmt[tid] + gd[tid] + den + 1e-8f);
      }
      __syncthreads();
    }
  }

  // epilogue: out affine -> layernorm -> head matmul (reuse pnd as scratch)
  float* ov  = (float*)pnd;
  float* lnv = ov + 128;
  float* mv  = ov + 256;
  if (tid < 128) ov[tid] = fmaf(v[tid], ow[tid], ob[tid]);
  __syncthreads();
  if (tid < 64) {
    float a = ov[tid], c = ov[tid + 64];
    float s = a + c, s2 = a * a + c * c;
    #pragma unroll
    for (int m = 1; m < 64; m <<= 1) {
      s += __shfl_xor(s, m, 64);
      s2 += __shfl_xor(s2, m, 64);
    }
    if (tid == 0) {
      float mean = s * (1.f / 128.f);
      float var = s2 * (1.f / 128.f) - mean * mean;
      mv[0] = mean;
      mv[1] = rsqrtf(var + 1e-5f);
    }
  }
  __syncthreads();
  if (tid < 128) lnv[tid] = fmaf((ov[tid] - mv[0]) * mv[1], lng[tid], lnb[tid]);
  __syncthreads();
  if (tid < 15) {
    float acc = hb[tid];
    const float* wr = hW + tid * 128;
    #pragma unroll
    for (int k = 0; k < 128; k += 4) {
      float4 wv = *(const float4*)(wr + k);
      acc = fmaf(wv.x, lnv[k], acc);
      acc = fmaf(wv.y, lnv[k + 1], acc);
      acc = fmaf(wv.z, lnv[k + 2], acc);
      acc = fmaf(wv.w, lnv[k + 3], acc);
    }
    out[b * 15 + tid] = acc;
  }
}

// ---------------- launch ----------------
extern "C" void kernel_launch(void* const* d_in, const int* in_sizes, int n_in,
                              void* d_out, int out_size, void* d_ws, size_t ws_size,
                              hipStream_t stream) {
  const float* x      = (const float*)d_in[0];
  const float* pre_W  = (const float*)d_in[1];
  const float* pre_b  = (const float*)d_in[2];
  const float* plg    = (const float*)d_in[3];
  const float* plb    = (const float*)d_in[4];
  const float* gleak  = (const float*)d_in[5];
  const float* vleak  = (const float*)d_in[6];
  const float* cm     = (const float*)d_in[7];
  const float* sigma  = (const float*)d_in[8];
  const float* mu     = (const float*)d_in[9];
  const float* w      = (const float*)d_in[10];
  const float* erev   = (const float*)d_in[11];
  const float* ss     = (const float*)d_in[12];
  const float* smu    = (const float*)d_in[13];
  const float* sw     = (const float*)d_in[14];
  const float* serev  = (const float*)d_in[15];
  const float* iw     = (const float*)d_in[16];
  const float* ib     = (const float*)d_in[17];
  const float* ow     = (const float*)d_in[18];
  const float* ob     = (const float*)d_in[19];
  const float* lng    = (const float*)d_in[20];
  const float* lnb    = (const float*)d_in[21];
  const float* hW     = (const float*)d_in[22];
  const float* hb     = (const float*)d_in[23];
  float* out = (float*)d_out;

  char* ws = (char*)d_ws;
  PK* Prec    = (PK*)ws;                              // 128 KB
  PK* Psen    = (PK*)(ws + 131072);                   // 128 KB
  float* vecs = (float*)(ws + 262144);                // 1.5 KB
  uint4* hbf  = (uint4*)(ws + 524288);                // 32 MB  (bf16 h_ln)
  unsigned* ndg = (unsigned*)(ws + 524288 + 33554432);// 64 MB  (bf16 num|den)

  prep_kernel<<<129, 256, 0, stream>>>(sigma, mu, w, erev, ss, smu, sw, serev,
                                       iw, ib, gleak, vleak, cm, Prec, Psen, vecs);
  stage_a<<<4096, 256, 84480, stream>>>(x, pre_W, pre_b, plg, plb, hbf);
  sensory_kernel<<<256, 512, 135680, stream>>>(Psen, hbf, ndg);
  ltc_scan<<<128, 512, 137728, stream>>>(Prec, vecs, ndg, ow, ob, lng, lnb, hW, hb, out);
}

// Round 2
// 5465.866 us; speedup vs baseline: 1.2585x; 1.2585x over previous
//
#include <hip/hip_runtime.h>

#define LOG2E 1.4426950408889634f

__device__ __forceinline__ unsigned short f2bf(float f) {
  unsigned u = __float_as_uint(f);
  u += 0x7FFFu + ((u >> 16) & 1u);            // round-to-nearest-even
  return (unsigned short)(u >> 16);
}
__device__ __forceinline__ unsigned pk2(float a, float b) {
  return (unsigned)f2bf(a) | ((unsigned)f2bf(b) << 16);
}
__device__ __forceinline__ float bl16(unsigned u) { return __uint_as_float(u << 16); }
__device__ __forceinline__ float bh16(unsigned u) { return __uint_as_float(u & 0xFFFF0000u); }

// sigmoid-weighted accumulate, f32 params (no unpack):
// t = c2 - a2*vi = log2e*sigma*(mu - vi); e = 2^t; sig = 1/(1+e)
// an += we*sig; ad += |we|*sig  (|we| is a free VOP3 input modifier)
__device__ __forceinline__ void sigacc3(float c2, float a2, float we, float vi,
                                        float& an, float& ad) {
  float t = fmaf(-a2, vi, c2);
  float e = __builtin_amdgcn_exp2f(t);
  float r = __builtin_amdgcn_rcpf(1.0f + e);
  an = fmaf(we, r, an);
  ad = fmaf(fabsf(we), r, ad);
}

// ---------------- prep: fold constants, softplus, emit f32 SoA-in-float4 ----------------
__global__ __launch_bounds__(256) void prep_kernel(
    const float* __restrict__ sigma, const float* __restrict__ mu,
    const float* __restrict__ w,     const float* __restrict__ erev,
    const float* __restrict__ ss,    const float* __restrict__ smu,
    const float* __restrict__ sw,    const float* __restrict__ serev,
    const float* __restrict__ iw,    const float* __restrict__ ib,
    const float* __restrict__ gleak, const float* __restrict__ vleak,
    const float* __restrict__ cm,
    float4* __restrict__ Prec4, float4* __restrict__ Psen4, float* __restrict__ vecs)
{
  int gid = blockIdx.x * 256 + threadIdx.x;
  if (gid < 16384) {
    float a2 = sigma[gid] * LOG2E;
    float c2 = a2 * mu[gid];
    float sp = log1pf(expf(w[gid]));          // softplus(w)
    float we = sp * erev[gid];                // erev = +-1
    Prec4[gid] = make_float4(c2, a2, we, 0.f);
  } else if (gid < 32768) {
    int e = gid - 16384;
    int i = e >> 7;                           // sensory row (D dim)
    float a2 = ss[e] * iw[i] * LOG2E;         // fold input_w
    float c2 = ss[e] * (smu[e] - ib[i]) * LOG2E; // fold input_b
    float sp = log1pf(expf(sw[e]));
    float we = sp * serev[e];
    Psen4[e] = make_float4(c2, a2, we, 0.f);
  } else if (gid < 32896) {
    int jj = gid - 32768;
    float gp = log1pf(expf(gleak[jj]));
    vecs[jj]       = log1pf(expf(cm[jj])) * 4.0f; // cm_t = softplus(cm)*ODE_UNFOLDS
    vecs[128 + jj] = gp;                          // gleak_p
    vecs[256 + jj] = gp * vleak[jj];              // gleak_p * vleak
  }
}

// ---------------- stage A: h = LN(x @ W^T + b), write bf16 (unchanged, known-good) ----------------
__global__ __launch_bounds__(256) void stage_a(
    const float* __restrict__ x, const float* __restrict__ W,
    const float* __restrict__ pb, const float* __restrict__ lg,
    const float* __restrict__ lb, uint4* __restrict__ hout)
{
  extern __shared__ char smem[];
  float* Wt = (float*)smem;            // [128][132] transposed W (k-major), padded
  float* xs = Wt + 128 * 132;          // [32][132]
  const int tid = threadIdx.x;

  #pragma unroll
  for (int ii = 0; ii < 16; ++ii) {
    int f = tid + (ii << 8);
    int jrow = f >> 5, kq = f & 31;
    float4 wv = ((const float4*)W)[f];
    float* wd = Wt + jrow;
    wd[(4 * kq + 0) * 132] = wv.x;
    wd[(4 * kq + 1) * 132] = wv.y;
    wd[(4 * kq + 2) * 132] = wv.z;
    wd[(4 * kq + 3) * 132] = wv.w;
  }
  const size_t R0 = (size_t)blockIdx.x << 5;   // 32 rows per block
  const float4* xg = (const float4*)(x + (R0 << 7));
  #pragma unroll
  for (int ii = 0; ii < 4; ++ii) {
    int f = tid + (ii << 8);
    int r = f >> 5, kq = f & 31;
    *(float4*)(xs + r * 132 + (kq << 2)) = xg[f];
  }
  __syncthreads();

  const int tr = tid >> 4, tc = tid & 15;
  const int r0 = tr << 1, j0 = tc << 3;
  float a0[8], a1[8];
  #pragma unroll
  for (int c = 0; c < 8; ++c) { a0[c] = 0.f; a1[c] = 0.f; }
  const float* xr0 = xs + r0 * 132;
  const float* xr1 = xs + (r0 + 1) * 132;
  const float* wc = Wt + j0;
  for (int k = 0; k < 128; k += 4) {
    float4 xa = *(const float4*)(xr0 + k);
    float4 xb = *(const float4*)(xr1 + k);
    #pragma unroll
    for (int s = 0; s < 4; ++s) {
      float4 w0 = *(const float4*)(wc + (k + s) * 132);
      float4 w1 = *(const float4*)(wc + (k + s) * 132 + 4);
      float xav = s == 0 ? xa.x : s == 1 ? xa.y : s == 2 ? xa.z : xa.w;
      float xbv = s == 0 ? xb.x : s == 1 ? xb.y : s == 2 ? xb.z : xb.w;
      a0[0] = fmaf(xav, w0.x, a0[0]); a0[1] = fmaf(xav, w0.y, a0[1]);
      a0[2] = fmaf(xav, w0.z, a0[2]); a0[3] = fmaf(xav, w0.w, a0[3]);
      a0[4] = fmaf(xav, w1.x, a0[4]); a0[5] = fmaf(xav, w1.y, a0[5]);
      a0[6] = fmaf(xav, w1.z, a0[6]); a0[7] = fmaf(xav, w1.w, a0[7]);
      a1[0] = fmaf(xbv, w0.x, a1[0]); a1[1] = fmaf(xbv, w0.y, a1[1]);
      a1[2] = fmaf(xbv, w0.z, a1[2]); a1[3] = fmaf(xbv, w0.w, a1[3]);
      a1[4] = fmaf(xbv, w1.x, a1[4]); a1[5] = fmaf(xbv, w1.y, a1[5]);
      a1[6] = fmaf(xbv, w1.z, a1[6]); a1[7] = fmaf(xbv, w1.w, a1[7]);
    }
  }
  float4 pb0 = *(const float4*)(pb + j0);
  float4 pb1 = *(const float4*)(pb + j0 + 4);
  a0[0] += pb0.x; a0[1] += pb0.y; a0[2] += pb0.z; a0[3] += pb0.w;
  a0[4] += pb1.x; a0[5] += pb1.y; a0[6] += pb1.z; a0[7] += pb1.w;
  a1[0] += pb0.x; a1[1] += pb0.y; a1[2] += pb0.z; a1[3] += pb0.w;
  a1[4] += pb1.x; a1[5] += pb1.y; a1[6] += pb1.z; a1[7] += pb1.w;
  float s0 = 0, q0 = 0, s1 = 0, q1 = 0;
  #pragma unroll
  for (int c = 0; c < 8; ++c) {
    s0 += a0[c]; q0 = fmaf(a0[c], a0[c], q0);
    s1 += a1[c]; q1 = fmaf(a1[c], a1[c], q1);
  }
  #pragma unroll
  for (int m = 1; m < 16; m <<= 1) {
    s0 += __shfl_xor(s0, m, 64); q0 += __shfl_xor(q0, m, 64);
    s1 += __shfl_xor(s1, m, 64); q1 += __shfl_xor(q1, m, 64);
  }
  float mu0 = s0 * (1.f / 128.f), mu1 = s1 * (1.f / 128.f);
  float rs0 = rsqrtf(fmaf(-mu0, mu0, q0 * (1.f / 128.f)) + 1e-5f);
  float rs1 = rsqrtf(fmaf(-mu1, mu1, q1 * (1.f / 128.f)) + 1e-5f);
  float4 g0 = *(const float4*)(lg + j0), g1 = *(const float4*)(lg + j0 + 4);
  float4 b0 = *(const float4*)(lb + j0), b1 = *(const float4*)(lb + j0 + 4);
  float n0[8], n1[8];
  const float* gv = (const float*)&g0; const float* bv = (const float*)&b0;
  #pragma unroll
  for (int c = 0; c < 4; ++c) {
    n0[c] = fmaf((a0[c] - mu0) * rs0, gv[c], bv[c]);
    n1[c] = fmaf((a1[c] - mu1) * rs1, gv[c], bv[c]);
  }
  const float* gv1 = (const float*)&g1; const float* bv1 = (const float*)&b1;
  #pragma unroll
  for (int c = 0; c < 4; ++c) {
    n0[4 + c] = fmaf((a0[4 + c] - mu0) * rs0, gv1[c], bv1[c]);
    n1[4 + c] = fmaf((a1[4 + c] - mu1) * rs1, gv1[c], bv1[c]);
  }
  uint4 o0, o1;
  o0.x = pk2(n0[0], n0[1]); o0.y = pk2(n0[2], n0[3]);
  o0.z = pk2(n0[4], n0[5]); o0.w = pk2(n0[6], n0[7]);
  o1.x = pk2(n1[0], n1[1]); o1.y = pk2(n1[2], n1[3]);
  o1.z = pk2(n1[4], n1[5]); o1.w = pk2(n1[6], n1[7]);
  hout[(R0 + r0) * 16 + tc] = o0;
  hout[(R0 + r0 + 1) * 16 + tc] = o1;
}

// ---------------- stage B: sensory terms — reg params, no LDS, no barriers ----------------
// layout: wave w (16 waves), lane: iq = lane&7 (i-octant), jj = lane>>3; j = w*8+jj
// thread covers i = iq*16 .. iq*16+15 for unit j; reduce over iq via shfl_xor 1,2,4
__global__ __launch_bounds__(1024, 4) void sensory_kernel(
    const float4* __restrict__ Pg4, const uint4* __restrict__ hbf,
    unsigned* __restrict__ ndg)
{
  const int tid = threadIdx.x;
  const int lane = tid & 63, wv = tid >> 6;
  const int iq = lane & 7, jj = lane >> 3;
  const int j = wv * 8 + jj;

  float c2s[16], a2s[16], wes[16];
  #pragma unroll
  for (int k = 0; k < 16; ++k) {
    float4 p = Pg4[(iq * 16 + k) * 128 + j];
    c2s[k] = p.x; a2s[k] = p.y; wes[k] = p.z;
  }

  const int p0 = blockIdx.x << 9;        // 512 pairs per block
  uint4 hc0 = hbf[((size_t)p0 << 4) + iq * 2];
  uint4 hc1 = hbf[((size_t)p0 << 4) + iq * 2 + 1];

  for (int q = 0; q < 512; ++q) {
    const int p = p0 + q;
    const int pn = p0 + (q + 1 < 512 ? q + 1 : q);
    uint4 hn0 = hbf[((size_t)pn << 4) + iq * 2];
    uint4 hn1 = hbf[((size_t)pn << 4) + iq * 2 + 1];

    float hv[16];
    hv[0] = bl16(hc0.x);  hv[1] = bh16(hc0.x);
    hv[2] = bl16(hc0.y);  hv[3] = bh16(hc0.y);
    hv[4] = bl16(hc0.z);  hv[5] = bh16(hc0.z);
    hv[6] = bl16(hc0.w);  hv[7] = bh16(hc0.w);
    hv[8] = bl16(hc1.x);  hv[9] = bh16(hc1.x);
    hv[10] = bl16(hc1.y); hv[11] = bh16(hc1.y);
    hv[12] = bl16(hc1.z); hv[13] = bh16(hc1.z);
    hv[14] = bl16(hc1.w); hv[15] = bh16(hc1.w);

    float an = 0.f, ad = 0.f;
    #pragma unroll
    for (int k = 0; k < 16; ++k)
      sigacc3(c2s[k], a2s[k], wes[k], hv[k], an, ad);

    #pragma unroll
    for (int m = 1; m <= 4; m <<= 1) {
      an += __shfl_xor(an, m, 64);
      ad += __shfl_xor(ad, m, 64);
    }
    if (iq == 0) ndg[((size_t)p << 7) + j] = pk2(an, ad);
    hc0 = hn0; hc1 = hn1;
  }
}

// ---------------- stage C: sequential LTC scan — reg params, 1 barrier/unfold ----------------
__global__ __launch_bounds__(1024, 4) void ltc_scan(
    const float4* __restrict__ Pg4, const float* __restrict__ vecs,
    const unsigned* __restrict__ ndg,
    const float* __restrict__ ow, const float* __restrict__ ob,
    const float* __restrict__ lng, const float* __restrict__ lnb,
    const float* __restrict__ hW, const float* __restrict__ hb,
    float* __restrict__ out)
{
  __shared__ float vbuf[2][128];
  __shared__ float ov[128], lnv[128], mv[2];

  const int tid = threadIdx.x;
  const int lane = tid & 63, wv = tid >> 6;
  const int iq = lane & 7, jj = lane >> 3;
  const int j = wv * 8 + jj;
  const int b = blockIdx.x;

  float c2s[16], a2s[16], wes[16];
  #pragma unroll
  for (int k = 0; k < 16; ++k) {
    float4 p = Pg4[(iq * 16 + k) * 128 + j];
    c2s[k] = p.x; a2s[k] = p.y; wes[k] = p.z;
  }
  const float cmtj = vecs[j];        // broadcast loads (same addr across iq dups)
  const float gdj  = vecs[128 + j];
  const float gnj  = vecs[256 + j];
  float vj = 0.f;
  if (tid < 128) vbuf[0][tid] = 0.f;
  __syncthreads();

  const size_t ndbase = ((size_t)b << 17) + j;   // b*1024*128 + j
  unsigned ndc = ndg[ndbase];                    // t = 0 sensory terms
  for (int t = 0; t < 1024; ++t) {
    const int tn = (t + 1 < 1024) ? t + 1 : 1023;
    unsigned ndn = ndg[ndbase + ((size_t)tn << 7)];   // prefetch next t
    const float snum = bl16(ndc), sden = bh16(ndc);
    #pragma unroll
    for (int u = 0; u < 4; ++u) {
      const float* vc = vbuf[u & 1];
      float an = 0.f, ad = 0.f;
      #pragma unroll
      for (int c = 0; c < 4; ++c) {
        float4 vv = *(const float4*)(vc + iq * 16 + 4 * c);
        sigacc3(c2s[4 * c + 0], a2s[4 * c + 0], wes[4 * c + 0], vv.x, an, ad);
        sigacc3(c2s[4 * c + 1], a2s[4 * c + 1], wes[4 * c + 1], vv.y, an, ad);
        sigacc3(c2s[4 * c + 2], a2s[4 * c + 2], wes[4 * c + 2], vv.z, an, ad);
        sigacc3(c2s[4 * c + 3], a2s[4 * c + 3], wes[4 * c + 3], vv.w, an, ad);
      }
      #pragma unroll
      for (int m = 1; m <= 4; m <<= 1) {
        an += __shfl_xor(an, m, 64);
        ad += __shfl_xor(ad, m, 64);
      }
      // all lanes compute vnew for their j (identical across iq dups) -> vj stays in reg
      float num = an + snum;
      float den = ad + sden;
      float vnew = (fmaf(cmtj, vj, gnj) + num) *
                   __builtin_amdgcn_rcpf(cmtj + gdj + den + 1e-8f);
      if (iq == 0) vbuf[(u & 1) ^ 1][j] = vnew;
      vj = vnew;
      __syncthreads();
    }
    ndc = ndn;
  }

  // epilogue: out affine -> layernorm -> head matmul (final v is in vbuf[0])
  if (tid < 128) ov[tid] = fmaf(vbuf[0][tid], ow[tid], ob[tid]);
  __syncthreads();
  if (tid < 64) {
    float a = ov[tid], c = ov[tid + 64];
    float s = a + c, s2 = fmaf(a, a, c * c);
    #pragma unroll
    for (int m = 1; m < 64; m <<= 1) {
      s += __shfl_xor(s, m, 64);
      s2 += __shfl_xor(s2, m, 64);
    }
    if (tid == 0) {
      float mean = s * (1.f / 128.f);
      float var = s2 * (1.f / 128.f) - mean * mean;
      mv[0] = mean;
      mv[1] = rsqrtf(var + 1e-5f);
    }
  }
  __syncthreads();
  if (tid < 128) lnv[tid] = fmaf((ov[tid] - mv[0]) * mv[1], lng[tid], lnb[tid]);
  __syncthreads();
  if (tid < 15) {
    float acc = hb[tid];
    const float* wr = hW + tid * 128;
    #pragma unroll
    for (int k = 0; k < 128; k += 4) {
      float4 wvv = *(const float4*)(wr + k);
      acc = fmaf(wvv.x, lnv[k], acc);
      acc = fmaf(wvv.y, lnv[k + 1], acc);
      acc = fmaf(wvv.z, lnv[k + 2], acc);
      acc = fmaf(wvv.w, lnv[k + 3], acc);
    }
    out[b * 15 + tid] = acc;
  }
}

// ---------------- launch ----------------
extern "C" void kernel_launch(void* const* d_in, const int* in_sizes, int n_in,
                              void* d_out, int out_size, void* d_ws, size_t ws_size,
                              hipStream_t stream) {
  const float* x      = (const float*)d_in[0];
  const float* pre_W  = (const float*)d_in[1];
  const float* pre_b  = (const float*)d_in[2];
  const float* plg    = (const float*)d_in[3];
  const float* plb    = (const float*)d_in[4];
  const float* gleak  = (const float*)d_in[5];
  const float* vleak  = (const float*)d_in[6];
  const float* cm     = (const float*)d_in[7];
  const float* sigma  = (const float*)d_in[8];
  const float* mu     = (const float*)d_in[9];
  const float* w      = (const float*)d_in[10];
  const float* erev   = (const float*)d_in[11];
  const float* ss     = (const float*)d_in[12];
  const float* smu    = (const float*)d_in[13];
  const float* sw     = (const float*)d_in[14];
  const float* serev  = (const float*)d_in[15];
  const float* iw     = (const float*)d_in[16];
  const float* ib     = (const float*)d_in[17];
  const float* ow     = (const float*)d_in[18];
  const float* ob     = (const float*)d_in[19];
  const float* lng    = (const float*)d_in[20];
  const float* lnb    = (const float*)d_in[21];
  const float* hW     = (const float*)d_in[22];
  const float* hb     = (const float*)d_in[23];
  float* out = (float*)d_out;

  char* ws = (char*)d_ws;
  float4* Prec4 = (float4*)ws;                            // 256 KB
  float4* Psen4 = (float4*)(ws + 262144);                 // 256 KB
  float* vecs   = (float*)(ws + 524288);                  // 1.5 KB
  uint4* hbf    = (uint4*)(ws + 1048576);                 // 32 MB (bf16 h_ln)
  unsigned* ndg = (unsigned*)(ws + 1048576 + 33554432);   // 64 MB (bf16 num|den)

  prep_kernel<<<129, 256, 0, stream>>>(sigma, mu, w, erev, ss, smu, sw, serev,
                                       iw, ib, gleak, vleak, cm, Prec4, Psen4, vecs);
  stage_a<<<4096, 256, 84480, stream>>>(x, pre_W, pre_b, plg, plb, hbf);
  sensory_kernel<<<256, 1024, 0, stream>>>(Psen4, hbf, ndg);
  ltc_scan<<<128, 1024, 0, stream>>>(Prec4, vecs, ndg, ow, ob, lng, lnb, hW, hb, out);
}

// Round 3
// 4837.919 us; speedup vs baseline: 1.4218x; 1.1298x over previous
//
#include <hip/hip_runtime.h>

#define LOG2E 1.4426950408889634f

typedef float f32x2 __attribute__((ext_vector_type(2)));

__device__ __forceinline__ unsigned short f2bf(float f) {
  unsigned u = __float_as_uint(f);
  u += 0x7FFFu + ((u >> 16) & 1u);            // round-to-nearest-even
  return (unsigned short)(u >> 16);
}
__device__ __forceinline__ unsigned pk2(float a, float b) {
  return (unsigned)f2bf(a) | ((unsigned)f2bf(b) << 16);
}
__device__ __forceinline__ float bl16(unsigned u) { return __uint_as_float(u << 16); }
__device__ __forceinline__ float bh16(unsigned u) { return __uint_as_float(u & 0xFFFF0000u); }

// packed sigmoid-weighted accumulate: two (i,j) sites per call.
// t = c2 - a2*v (v_pk_fma); e = 2^t; s = 1+e (v_pk_add); r = 1/s
// an += we*r (v_pk_fma); ad += |we|*r (v_pk_fma)
__device__ __forceinline__ void sigacc2(f32x2 c2, f32x2 a2, f32x2 we, f32x2 aw,
                                        f32x2 vi, f32x2& an, f32x2& ad) {
  f32x2 t = c2 - a2 * vi;
  f32x2 e;
  e.x = __builtin_amdgcn_exp2f(t.x);
  e.y = __builtin_amdgcn_exp2f(t.y);
  f32x2 s = e + 1.0f;
  f32x2 r;
  r.x = __builtin_amdgcn_rcpf(s.x);
  r.y = __builtin_amdgcn_rcpf(s.y);
  an += we * r;
  ad += aw * r;
}

// ---------------- prep: fold constants, softplus, emit SoA [j][i] f32 ----------------
__global__ __launch_bounds__(256) void prep_kernel(
    const float* __restrict__ sigma, const float* __restrict__ mu,
    const float* __restrict__ w,     const float* __restrict__ erev,
    const float* __restrict__ ss,    const float* __restrict__ smu,
    const float* __restrict__ sw,    const float* __restrict__ serev,
    const float* __restrict__ iw,    const float* __restrict__ ib,
    const float* __restrict__ gleak, const float* __restrict__ vleak,
    const float* __restrict__ cm,
    float* __restrict__ C2r, float* __restrict__ A2r,
    float* __restrict__ WEr, float* __restrict__ AWr,
    float* __restrict__ C2s, float* __restrict__ A2s,
    float* __restrict__ WEs, float* __restrict__ AWs,
    float* __restrict__ vecs)
{
  int gid = blockIdx.x * 256 + threadIdx.x;
  if (gid < 16384) {
    int i = gid >> 7, j = gid & 127;
    int idx = j * 128 + i;                    // transposed SoA [j][i]
    float a2 = sigma[gid] * LOG2E;
    float c2 = a2 * mu[gid];
    float sp = log1pf(expf(w[gid]));          // softplus(w) > 0
    float we = sp * erev[gid];                // erev = +-1
    C2r[idx] = c2; A2r[idx] = a2; WEr[idx] = we; AWr[idx] = sp;
  } else if (gid < 32768) {
    int e = gid - 16384;
    int i = e >> 7, j = e & 127;
    int idx = j * 128 + i;
    float a2 = ss[e] * iw[i] * LOG2E;         // fold input_w
    float c2 = ss[e] * (smu[e] - ib[i]) * LOG2E; // fold input_b
    float sp = log1pf(expf(sw[e]));
    float we = sp * serev[e];
    C2s[idx] = c2; A2s[idx] = a2; WEs[idx] = we; AWs[idx] = sp;
  } else if (gid < 32896) {
    int jj = gid - 32768;
    float gp = log1pf(expf(gleak[jj]));
    vecs[jj]       = log1pf(expf(cm[jj])) * 4.0f; // cm_t = softplus(cm)*ODE_UNFOLDS
    vecs[128 + jj] = gp;                          // gleak_p
    vecs[256 + jj] = gp * vleak[jj];              // gleak_p * vleak
  }
}

// ---------------- stage A: h = LN(x @ W^T + b), write bf16 (unchanged, known-good) ----------------
__global__ __launch_bounds__(256) void stage_a(
    const float* __restrict__ x, const float* __restrict__ W,
    const float* __restrict__ pb, const float* __restrict__ lg,
    const float* __restrict__ lb, uint4* __restrict__ hout)
{
  extern __shared__ char smem[];
  float* Wt = (float*)smem;            // [128][132] transposed W (k-major), padded
  float* xs = Wt + 128 * 132;          // [32][132]
  const int tid = threadIdx.x;

  #pragma unroll
  for (int ii = 0; ii < 16; ++ii) {
    int f = tid + (ii << 8);
    int jrow = f >> 5, kq = f & 31;
    float4 wv = ((const float4*)W)[f];
    float* wd = Wt + jrow;
    wd[(4 * kq + 0) * 132] = wv.x;
    wd[(4 * kq + 1) * 132] = wv.y;
    wd[(4 * kq + 2) * 132] = wv.z;
    wd[(4 * kq + 3) * 132] = wv.w;
  }
  const size_t R0 = (size_t)blockIdx.x << 5;   // 32 rows per block
  const float4* xg = (const float4*)(x + (R0 << 7));
  #pragma unroll
  for (int ii = 0; ii < 4; ++ii) {
    int f = tid + (ii << 8);
    int r = f >> 5, kq = f & 31;
    *(float4*)(xs + r * 132 + (kq << 2)) = xg[f];
  }
  __syncthreads();

  const int tr = tid >> 4, tc = tid & 15;
  const int r0 = tr << 1, j0 = tc << 3;
  float a0[8], a1[8];
  #pragma unroll
  for (int c = 0; c < 8; ++c) { a0[c] = 0.f; a1[c] = 0.f; }
  const float* xr0 = xs + r0 * 132;
  const float* xr1 = xs + (r0 + 1) * 132;
  const float* wc = Wt + j0;
  for (int k = 0; k < 128; k += 4) {
    float4 xa = *(const float4*)(xr0 + k);
    float4 xb = *(const float4*)(xr1 + k);
    #pragma unroll
    for (int s = 0; s < 4; ++s) {
      float4 w0 = *(const float4*)(wc + (k + s) * 132);
      float4 w1 = *(const float4*)(wc + (k + s) * 132 + 4);
      float xav = s == 0 ? xa.x : s == 1 ? xa.y : s == 2 ? xa.z : xa.w;
      float xbv = s == 0 ? xb.x : s == 1 ? xb.y : s == 2 ? xb.z : xb.w;
      a0[0] = fmaf(xav, w0.x, a0[0]); a0[1] = fmaf(xav, w0.y, a0[1]);
      a0[2] = fmaf(xav, w0.z, a0[2]); a0[3] = fmaf(xav, w0.w, a0[3]);
      a0[4] = fmaf(xav, w1.x, a0[4]); a0[5] = fmaf(xav, w1.y, a0[5]);
      a0[6] = fmaf(xav, w1.z, a0[6]); a0[7] = fmaf(xav, w1.w, a0[7]);
      a1[0] = fmaf(xbv, w0.x, a1[0]); a1[1] = fmaf(xbv, w0.y, a1[1]);
      a1[2] = fmaf(xbv, w0.z, a1[2]); a1[3] = fmaf(xbv, w0.w, a1[3]);
      a1[4] = fmaf(xbv, w1.x, a1[4]); a1[5] = fmaf(xbv, w1.y, a1[5]);
      a1[6] = fmaf(xbv, w1.z, a1[6]); a1[7] = fmaf(xbv, w1.w, a1[7]);
    }
  }
  float4 pb0 = *(const float4*)(pb + j0);
  float4 pb1 = *(const float4*)(pb + j0 + 4);
  a0[0] += pb0.x; a0[1] += pb0.y; a0[2] += pb0.z; a0[3] += pb0.w;
  a0[4] += pb1.x; a0[5] += pb1.y; a0[6] += pb1.z; a0[7] += pb1.w;
  a1[0] += pb0.x; a1[1] += pb0.y; a1[2] += pb0.z; a1[3] += pb0.w;
  a1[4] += pb1.x; a1[5] += pb1.y; a1[6] += pb1.z; a1[7] += pb1.w;
  float s0 = 0, q0 = 0, s1 = 0, q1 = 0;
  #pragma unroll
  for (int c = 0; c < 8; ++c) {
    s0 += a0[c]; q0 = fmaf(a0[c], a0[c], q0);
    s1 += a1[c]; q1 = fmaf(a1[c], a1[c], q1);
  }
  #pragma unroll
  for (int m = 1; m < 16; m <<= 1) {
    s0 += __shfl_xor(s0, m, 64); q0 += __shfl_xor(q0, m, 64);
    s1 += __shfl_xor(s1, m, 64); q1 += __shfl_xor(q1, m, 64);
  }
  float mu0 = s0 * (1.f / 128.f), mu1 = s1 * (1.f / 128.f);
  float rs0 = rsqrtf(fmaf(-mu0, mu0, q0 * (1.f / 128.f)) + 1e-5f);
  float rs1 = rsqrtf(fmaf(-mu1, mu1, q1 * (1.f / 128.f)) + 1e-5f);
  float4 g0 = *(const float4*)(lg + j0), g1 = *(const float4*)(lg + j0 + 4);
  float4 b0 = *(const float4*)(lb + j0), b1 = *(const float4*)(lb + j0 + 4);
  float n0[8], n1[8];
  const float* gv = (const float*)&g0; const float* bv = (const float*)&b0;
  #pragma unroll
  for (int c = 0; c < 4; ++c) {
    n0[c] = fmaf((a0[c] - mu0) * rs0, gv[c], bv[c]);
    n1[c] = fmaf((a1[c] - mu1) * rs1, gv[c], bv[c]);
  }
  const float* gv1 = (const float*)&g1; const float* bv1 = (const float*)&b1;
  #pragma unroll
  for (int c = 0; c < 4; ++c) {
    n0[4 + c] = fmaf((a0[4 + c] - mu0) * rs0, gv1[c], bv1[c]);
    n1[4 + c] = fmaf((a1[4 + c] - mu1) * rs1, gv1[c], bv1[c]);
  }
  uint4 o0, o1;
  o0.x = pk2(n0[0], n0[1]); o0.y = pk2(n0[2], n0[3]);
  o0.z = pk2(n0[4], n0[5]); o0.w = pk2(n0[6], n0[7]);
  o1.x = pk2(n1[0], n1[1]); o1.y = pk2(n1[2], n1[3]);
  o1.z = pk2(n1[4], n1[5]); o1.w = pk2(n1[6], n1[7]);
  hout[(R0 + r0) * 16 + tc] = o0;
  hout[(R0 + r0 + 1) * 16 + tc] = o1;
}

// ---------------- stage B: sensory terms — reg params (packed), no LDS ----------------
__global__ __launch_bounds__(1024, 4) void sensory_kernel(
    const float* __restrict__ C2, const float* __restrict__ A2,
    const float* __restrict__ WE, const float* __restrict__ AW,
    const uint4* __restrict__ hbf, unsigned* __restrict__ ndg)
{
  const int tid = threadIdx.x;
  const int lane = tid & 63, wv = tid >> 6;
  const int iq = lane & 7, jj = lane >> 3;
  const int j = wv * 8 + jj;

  f32x2 c22[8], a22[8], we2[8], aw2[8];
  const int pbase = j * 128 + iq * 16;
  #pragma unroll
  for (int p = 0; p < 8; ++p) {
    c22[p] = *(const f32x2*)(C2 + pbase + 2 * p);
    a22[p] = *(const f32x2*)(A2 + pbase + 2 * p);
    we2[p] = *(const f32x2*)(WE + pbase + 2 * p);
    aw2[p] = *(const f32x2*)(AW + pbase + 2 * p);
  }

  const int p0 = blockIdx.x << 9;        // 512 pairs per block
  uint4 hc0 = hbf[((size_t)p0 << 4) + iq * 2];
  uint4 hc1 = hbf[((size_t)p0 << 4) + iq * 2 + 1];

  for (int q = 0; q < 512; ++q) {
    const int p = p0 + q;
    const int pn = p0 + (q + 1 < 512 ? q + 1 : q);
    uint4 hn0 = hbf[((size_t)pn << 4) + iq * 2];
    uint4 hn1 = hbf[((size_t)pn << 4) + iq * 2 + 1];

    f32x2 hv[8];
    hv[0].x = bl16(hc0.x); hv[0].y = bh16(hc0.x);
    hv[1].x = bl16(hc0.y); hv[1].y = bh16(hc0.y);
    hv[2].x = bl16(hc0.z); hv[2].y = bh16(hc0.z);
    hv[3].x = bl16(hc0.w); hv[3].y = bh16(hc0.w);
    hv[4].x = bl16(hc1.x); hv[4].y = bh16(hc1.x);
    hv[5].x = bl16(hc1.y); hv[5].y = bh16(hc1.y);
    hv[6].x = bl16(hc1.z); hv[6].y = bh16(hc1.z);
    hv[7].x = bl16(hc1.w); hv[7].y = bh16(hc1.w);

    f32x2 an2 = {0.f, 0.f}, ad2 = {0.f, 0.f};
    #pragma unroll
    for (int p8 = 0; p8 < 8; ++p8)
      sigacc2(c22[p8], a22[p8], we2[p8], aw2[p8], hv[p8], an2, ad2);

    float an = an2.x + an2.y, ad = ad2.x + ad2.y;
    #pragma unroll
    for (int m = 1; m <= 4; m <<= 1) {
      an += __shfl_xor(an, m, 64);
      ad += __shfl_xor(ad, m, 64);
    }
    if (iq == 0) ndg[((size_t)p << 7) + j] = pk2(an, ad);
    hc0 = hn0; hc1 = hn1;
  }
}

// ---------------- stage C: sequential LTC scan — packed math, stride-36 v layout ----------------
// v_i lives at vbuf[buf][(i>>4)*36 + (i&15)]: the 8 iq-groups' ds_read_b128 hit
// banks (iq*4 + 4c)%32 — disjoint 4-bank sets, zero conflict.
__global__ __launch_bounds__(1024, 4) void ltc_scan(
    const float* __restrict__ C2, const float* __restrict__ A2,
    const float* __restrict__ WE, const float* __restrict__ AW,
    const float* __restrict__ vecs, const unsigned* __restrict__ ndg,
    const float* __restrict__ ow, const float* __restrict__ ob,
    const float* __restrict__ lng, const float* __restrict__ lnb,
    const float* __restrict__ hW, const float* __restrict__ hb,
    float* __restrict__ out)
{
  __shared__ float vbuf[2][8 * 36];
  __shared__ float ov[128], lnv[128], mv[2];

  const int tid = threadIdx.x;
  const int lane = tid & 63, wv = tid >> 6;
  const int iq = lane & 7, jj = lane >> 3;
  const int j = wv * 8 + jj;
  const int b = blockIdx.x;
  const int vpos_j = ((j >> 4) * 36) + (j & 15);

  f32x2 c22[8], a22[8], we2[8], aw2[8];
  const int pbase = j * 128 + iq * 16;
  #pragma unroll
  for (int p = 0; p < 8; ++p) {
    c22[p] = *(const f32x2*)(C2 + pbase + 2 * p);
    a22[p] = *(const f32x2*)(A2 + pbase + 2 * p);
    we2[p] = *(const f32x2*)(WE + pbase + 2 * p);
    aw2[p] = *(const f32x2*)(AW + pbase + 2 * p);
  }
  const float cmtj = vecs[j];
  const float gdj  = vecs[128 + j];
  const float gnj  = vecs[256 + j];
  float vj = 0.f;
  if (tid < 128) vbuf[0][((tid >> 4) * 36) + (tid & 15)] = 0.f;
  __syncthreads();

  const size_t ndbase = ((size_t)b << 17) + j;   // b*1024*128 + j
  unsigned ndc = ndg[ndbase];                    // t = 0 sensory terms
  for (int t = 0; t < 1024; ++t) {
    const int tn = (t + 1 < 1024) ? t + 1 : 1023;
    unsigned ndn = ndg[ndbase + ((size_t)tn << 7)];   // prefetch next t
    const float snum = bl16(ndc), sden = bh16(ndc);
    #pragma unroll
    for (int u = 0; u < 4; ++u) {
      const float* vc = vbuf[u & 1] + iq * 36;
      f32x2 an2 = {0.f, 0.f}, ad2 = {0.f, 0.f};
      #pragma unroll
      for (int c = 0; c < 4; ++c) {
        float4 vv = *(const float4*)(vc + 4 * c);
        f32x2 vA; vA.x = vv.x; vA.y = vv.y;
        f32x2 vB; vB.x = vv.z; vB.y = vv.w;
        sigacc2(c22[2 * c],     a22[2 * c],     we2[2 * c],     aw2[2 * c],     vA, an2, ad2);
        sigacc2(c22[2 * c + 1], a22[2 * c + 1], we2[2 * c + 1], aw2[2 * c + 1], vB, an2, ad2);
      }
      float an = an2.x + an2.y, ad = ad2.x + ad2.y;
      #pragma unroll
      for (int m = 1; m <= 4; m <<= 1) {
        an += __shfl_xor(an, m, 64);
        ad += __shfl_xor(ad, m, 64);
      }
      // all lanes compute vnew for their j (identical across iq dups) -> vj stays in reg
      float num = an + snum;
      float den = ad + sden;
      float vnew = (fmaf(cmtj, vj, gnj) + num) *
                   __builtin_amdgcn_rcpf(cmtj + gdj + den + 1e-8f);
      if (iq == 0) vbuf[(u & 1) ^ 1][vpos_j] = vnew;
      vj = vnew;
      __syncthreads();
    }
    ndc = ndn;
  }

  // epilogue: out affine -> layernorm -> head matmul (final v is in vbuf[0], padded layout)
  if (tid < 128)
    ov[tid] = fmaf(vbuf[0][((tid >> 4) * 36) + (tid & 15)], ow[tid], ob[tid]);
  __syncthreads();
  if (tid < 64) {
    float a = ov[tid], c = ov[tid + 64];
    float s = a + c, s2 = fmaf(a, a, c * c);
    #pragma unroll
    for (int m = 1; m < 64; m <<= 1) {
      s += __shfl_xor(s, m, 64);
      s2 += __shfl_xor(s2, m, 64);
    }
    if (tid == 0) {
      float mean = s * (1.f / 128.f);
      float var = s2 * (1.f / 128.f) - mean * mean;
      mv[0] = mean;
      mv[1] = rsqrtf(var + 1e-5f);
    }
  }
  __syncthreads();
  if (tid < 128) lnv[tid] = fmaf((ov[tid] - mv[0]) * mv[1], lng[tid], lnb[tid]);
  __syncthreads();
  if (tid < 15) {
    float acc = hb[tid];
    const float* wr = hW + tid * 128;
    #pragma unroll
    for (int k = 0; k < 128; k += 4) {
      float4 wvv = *(const float4*)(wr + k);
      acc = fmaf(wvv.x, lnv[k], acc);
      acc = fmaf(wvv.y, lnv[k + 1], acc);
      acc = fmaf(wvv.z, lnv[k + 2], acc);
      acc = fmaf(wvv.w, lnv[k + 3], acc);
    }
    out[b * 15 + tid] = acc;
  }
}

// ---------------- launch ----------------
extern "C" void kernel_launch(void* const* d_in, const int* in_sizes, int n_in,
                              void* d_out, int out_size, void* d_ws, size_t ws_size,
                              hipStream_t stream) {
  const float* x      = (const float*)d_in[0];
  const float* pre_W  = (const float*)d_in[1];
  const float* pre_b  = (const float*)d_in[2];
  const float* plg    = (const float*)d_in[3];
  const float* plb    = (const float*)d_in[4];
  const float* gleak  = (const float*)d_in[5];
  const float* vleak  = (const float*)d_in[6];
  const float* cm     = (const float*)d_in[7];
  const float* sigma  = (const float*)d_in[8];
  const float* mu     = (const float*)d_in[9];
  const float* w      = (const float*)d_in[10];
  const float* erev   = (const float*)d_in[11];
  const float* ss     = (const float*)d_in[12];
  const float* smu    = (const float*)d_in[13];
  const float* sw     = (const float*)d_in[14];
  const float* serev  = (const float*)d_in[15];
  const float* iw     = (const float*)d_in[16];
  const float* ib     = (const float*)d_in[17];
  const float* ow     = (const float*)d_in[18];
  const float* ob     = (const float*)d_in[19];
  const float* lng    = (const float*)d_in[20];
  const float* lnb    = (const float*)d_in[21];
  const float* hW     = (const float*)d_in[22];
  const float* hb     = (const float*)d_in[23];
  float* out = (float*)d_out;

  char* ws = (char*)d_ws;
  float* C2r = (float*)(ws + 0 * 65536);
  float* A2r = (float*)(ws + 1 * 65536);
  float* WEr = (float*)(ws + 2 * 65536);
  float* AWr = (float*)(ws + 3 * 65536);
  float* C2s = (float*)(ws + 4 * 65536);
  float* A2s = (float*)(ws + 5 * 65536);
  float* WEs = (float*)(ws + 6 * 65536);
  float* AWs = (float*)(ws + 7 * 65536);
  float* vecs   = (float*)(ws + 8 * 65536);               // 1.5 KB
  uint4* hbf    = (uint4*)(ws + 1048576);                 // 32 MB (bf16 h_ln)
  unsigned* ndg = (unsigned*)(ws + 1048576 + 33554432);   // 64 MB (bf16 num|den)

  prep_kernel<<<129, 256, 0, stream>>>(sigma, mu, w, erev, ss, smu, sw, serev,
                                       iw, ib, gleak, vleak, cm,
                                       C2r, A2r, WEr, AWr, C2s, A2s, WEs, AWs, vecs);
  stage_a<<<4096, 256, 84480, stream>>>(x, pre_W, pre_b, plg, plb, hbf);
  sensory_kernel<<<256, 1024, 0, stream>>>(C2s, A2s, WEs, AWs, hbf, ndg);
  ltc_scan<<<128, 1024, 0, stream>>>(C2r, A2r, WEr, AWr, vecs, ndg,
                                     ow, ob, lng, lnb, hW, hb, out);
}

// Round 4
// 4339.764 us; speedup vs baseline: 1.5850x; 1.1148x over previous
//
#include <hip/hip_runtime.h>

#define LOG2E 1.4426950408889634f

typedef float f32x2 __attribute__((ext_vector_type(2)));

__device__ __forceinline__ unsigned short f2bf(float f) {
  unsigned u = __float_as_uint(f);
  u += 0x7FFFu + ((u >> 16) & 1u);            // round-to-nearest-even
  return (unsigned short)(u >> 16);
}
__device__ __forceinline__ unsigned pk2(float a, float b) {
  return (unsigned)f2bf(a) | ((unsigned)f2bf(b) << 16);
}
__device__ __forceinline__ float bl16(unsigned u) { return __uint_as_float(u << 16); }
__device__ __forceinline__ float bh16(unsigned u) { return __uint_as_float(u & 0xFFFF0000u); }

// DPP cross-lane adds (VALU pipe, no LDS): reduce over 8 consecutive lanes.
// 0xB1 = quad_perm(1,0,3,2) -> lane^1 ; 0x4E = quad_perm(2,3,0,1) -> lane^2
// 0x141 = row_half_mirror -> lane^7 within aligned 8-group (valid after quad
// reduction since all quad lanes hold the quad-sum).
__device__ __forceinline__ float dpp_xor1_add(float x) {
  return x + __int_as_float(__builtin_amdgcn_update_dpp(
      0, __float_as_int(x), 0xB1, 0xF, 0xF, true));
}
__device__ __forceinline__ float dpp_xor2_add(float x) {
  return x + __int_as_float(__builtin_amdgcn_update_dpp(
      0, __float_as_int(x), 0x4E, 0xF, 0xF, true));
}
__device__ __forceinline__ float dpp_xor7_add(float x) {
  return x + __int_as_float(__builtin_amdgcn_update_dpp(
      0, __float_as_int(x), 0x141, 0xF, 0xF, true));
}
__device__ __forceinline__ float red8(float x) {
  x = dpp_xor1_add(x);
  x = dpp_xor2_add(x);
  x = dpp_xor7_add(x);
  return x;
}

// packed sigmoid-weighted accumulate: two (i,j) sites per call.
__device__ __forceinline__ void sigacc2(f32x2 c2, f32x2 a2, f32x2 we, f32x2 aw,
                                        f32x2 vi, f32x2& an, f32x2& ad) {
  f32x2 t = c2 - a2 * vi;
  f32x2 e;
  e.x = __builtin_amdgcn_exp2f(t.x);
  e.y = __builtin_amdgcn_exp2f(t.y);
  f32x2 s = e + 1.0f;
  f32x2 r;
  r.x = __builtin_amdgcn_rcpf(s.x);
  r.y = __builtin_amdgcn_rcpf(s.y);
  an += we * r;
  ad += aw * r;
}

// ---------------- prep: fold constants, softplus, emit SoA [j][i] f32 ----------------
__global__ __launch_bounds__(256) void prep_kernel(
    const float* __restrict__ sigma, const float* __restrict__ mu,
    const float* __restrict__ w,     const float* __restrict__ erev,
    const float* __restrict__ ss,    const float* __restrict__ smu,
    const float* __restrict__ sw,    const float* __restrict__ serev,
    const float* __restrict__ iw,    const float* __restrict__ ib,
    const float* __restrict__ gleak, const float* __restrict__ vleak,
    const float* __restrict__ cm,
    float* __restrict__ C2r, float* __restrict__ A2r,
    float* __restrict__ WEr, float* __restrict__ AWr,
    float* __restrict__ C2s, float* __restrict__ A2s,
    float* __restrict__ WEs, float* __restrict__ AWs,
    float* __restrict__ vecs)
{
  int gid = blockIdx.x * 256 + threadIdx.x;
  if (gid < 16384) {
    int i = gid >> 7, j = gid & 127;
    int idx = j * 128 + i;                    // transposed SoA [j][i]
    float a2 = sigma[gid] * LOG2E;
    float c2 = a2 * mu[gid];
    float sp = log1pf(expf(w[gid]));          // softplus(w) > 0
    float we = sp * erev[gid];                // erev = +-1
    C2r[idx] = c2; A2r[idx] = a2; WEr[idx] = we; AWr[idx] = sp;
  } else if (gid < 32768) {
    int e = gid - 16384;
    int i = e >> 7, j = e & 127;
    int idx = j * 128 + i;
    float a2 = ss[e] * iw[i] * LOG2E;         // fold input_w
    float c2 = ss[e] * (smu[e] - ib[i]) * LOG2E; // fold input_b
    float sp = log1pf(expf(sw[e]));
    float we = sp * serev[e];
    C2s[idx] = c2; A2s[idx] = a2; WEs[idx] = we; AWs[idx] = sp;
  } else if (gid < 32896) {
    int jj = gid - 32768;
    float gp = log1pf(expf(gleak[jj]));
    vecs[jj]       = log1pf(expf(cm[jj])) * 4.0f; // cm_t = softplus(cm)*ODE_UNFOLDS
    vecs[128 + jj] = gp;                          // gleak_p
    vecs[256 + jj] = gp * vleak[jj];              // gleak_p * vleak
  }
}

// ---------------- stage A: h = LN(x @ W^T + b), write bf16 (unchanged, known-good) ----------------
__global__ __launch_bounds__(256) void stage_a(
    const float* __restrict__ x, const float* __restrict__ W,
    const float* __restrict__ pb, const float* __restrict__ lg,
    const float* __restrict__ lb, uint4* __restrict__ hout)
{
  extern __shared__ char smem[];
  float* Wt = (float*)smem;            // [128][132] transposed W (k-major), padded
  float* xs = Wt + 128 * 132;          // [32][132]
  const int tid = threadIdx.x;

  #pragma unroll
  for (int ii = 0; ii < 16; ++ii) {
    int f = tid + (ii << 8);
    int jrow = f >> 5, kq = f & 31;
    float4 wv = ((const float4*)W)[f];
    float* wd = Wt + jrow;
    wd[(4 * kq + 0) * 132] = wv.x;
    wd[(4 * kq + 1) * 132] = wv.y;
    wd[(4 * kq + 2) * 132] = wv.z;
    wd[(4 * kq + 3) * 132] = wv.w;
  }
  const size_t R0 = (size_t)blockIdx.x << 5;   // 32 rows per block
  const float4* xg = (const float4*)(x + (R0 << 7));
  #pragma unroll
  for (int ii = 0; ii < 4; ++ii) {
    int f = tid + (ii << 8);
    int r = f >> 5, kq = f & 31;
    *(float4*)(xs + r * 132 + (kq << 2)) = xg[f];
  }
  __syncthreads();

  const int tr = tid >> 4, tc = tid & 15;
  const int r0 = tr << 1, j0 = tc << 3;
  float a0[8], a1[8];
  #pragma unroll
  for (int c = 0; c < 8; ++c) { a0[c] = 0.f; a1[c] = 0.f; }
  const float* xr0 = xs + r0 * 132;
  const float* xr1 = xs + (r0 + 1) * 132;
  const float* wc = Wt + j0;
  for (int k = 0; k < 128; k += 4) {
    float4 xa = *(const float4*)(xr0 + k);
    float4 xb = *(const float4*)(xr1 + k);
    #pragma unroll
    for (int s = 0; s < 4; ++s) {
      float4 w0 = *(const float4*)(wc + (k + s) * 132);
      float4 w1 = *(const float4*)(wc + (k + s) * 132 + 4);
      float xav = s == 0 ? xa.x : s == 1 ? xa.y : s == 2 ? xa.z : xa.w;
      float xbv = s == 0 ? xb.x : s == 1 ? xb.y : s == 2 ? xb.z : xb.w;
      a0[0] = fmaf(xav, w0.x, a0[0]); a0[1] = fmaf(xav, w0.y, a0[1]);
      a0[2] = fmaf(xav, w0.z, a0[2]); a0[3] = fmaf(xav, w0.w, a0[3]);
      a0[4] = fmaf(xav, w1.x, a0[4]); a0[5] = fmaf(xav, w1.y, a0[5]);
      a0[6] = fmaf(xav, w1.z, a0[6]); a0[7] = fmaf(xav, w1.w, a0[7]);
      a1[0] = fmaf(xbv, w0.x, a1[0]); a1[1] = fmaf(xbv, w0.y, a1[1]);
      a1[2] = fmaf(xbv, w0.z, a1[2]); a1[3] = fmaf(xbv, w0.w, a1[3]);
      a1[4] = fmaf(xbv, w1.x, a1[4]); a1[5] = fmaf(xbv, w1.y, a1[5]);
      a1[6] = fmaf(xbv, w1.z, a1[6]); a1[7] = fmaf(xbv, w1.w, a1[7]);
    }
  }
  float4 pb0 = *(const float4*)(pb + j0);
  float4 pb1 = *(const float4*)(pb + j0 + 4);
  a0[0] += pb0.x; a0[1] += pb0.y; a0[2] += pb0.z; a0[3] += pb0.w;
  a0[4] += pb1.x; a0[5] += pb1.y; a0[6] += pb1.z; a0[7] += pb1.w;
  a1[0] += pb0.x; a1[1] += pb0.y; a1[2] += pb0.z; a1[3] += pb0.w;
  a1[4] += pb1.x; a1[5] += pb1.y; a1[6] += pb1.z; a1[7] += pb1.w;
  float s0 = 0, q0 = 0, s1 = 0, q1 = 0;
  #pragma unroll
  for (int c = 0; c < 8; ++c) {
    s0 += a0[c]; q0 = fmaf(a0[c], a0[c], q0);
    s1 += a1[c]; q1 = fmaf(a1[c], a1[c], q1);
  }
  #pragma unroll
  for (int m = 1; m < 16; m <<= 1) {
    s0 += __shfl_xor(s0, m, 64); q0 += __shfl_xor(q0, m, 64);
    s1 += __shfl_xor(s1, m, 64); q1 += __shfl_xor(q1, m, 64);
  }
  float mu0 = s0 * (1.f / 128.f), mu1 = s1 * (1.f / 128.f);
  float rs0 = rsqrtf(fmaf(-mu0, mu0, q0 * (1.f / 128.f)) + 1e-5f);
  float rs1 = rsqrtf(fmaf(-mu1, mu1, q1 * (1.f / 128.f)) + 1e-5f);
  float4 g0 = *(const float4*)(lg + j0), g1 = *(const float4*)(lg + j0 + 4);
  float4 b0 = *(const float4*)(lb + j0), b1 = *(const float4*)(lb + j0 + 4);
  float n0[8], n1[8];
  const float* gv = (const float*)&g0; const float* bv = (const float*)&b0;
  #pragma unroll
  for (int c = 0; c < 4; ++c) {
    n0[c] = fmaf((a0[c] - mu0) * rs0, gv[c], bv[c]);
    n1[c] = fmaf((a1[c] - mu1) * rs1, gv[c], bv[c]);
  }
  const float* gv1 = (const float*)&g1; const float* bv1 = (const float*)&b1;
  #pragma unroll
  for (int c = 0; c < 4; ++c) {
    n0[4 + c] = fmaf((a0[4 + c] - mu0) * rs0, gv1[c], bv1[c]);
    n1[4 + c] = fmaf((a1[4 + c] - mu1) * rs1, gv1[c], bv1[c]);
  }
  uint4 o0, o1;
  o0.x = pk2(n0[0], n0[1]); o0.y = pk2(n0[2], n0[3]);
  o0.z = pk2(n0[4], n0[5]); o0.w = pk2(n0[6], n0[7]);
  o1.x = pk2(n1[0], n1[1]); o1.y = pk2(n1[2], n1[3]);
  o1.z = pk2(n1[4], n1[5]); o1.w = pk2(n1[6], n1[7]);
  hout[(R0 + r0) * 16 + tc] = o0;
  hout[(R0 + r0 + 1) * 16 + tc] = o1;
}

// ---------------- stage B: sensory terms — reg params (packed), DPP reduce ----------------
__global__ __launch_bounds__(1024, 4) void sensory_kernel(
    const float* __restrict__ C2, const float* __restrict__ A2,
    const float* __restrict__ WE, const float* __restrict__ AW,
    const uint4* __restrict__ hbf, unsigned* __restrict__ ndg)
{
  const int tid = threadIdx.x;
  const int lane = tid & 63, wv = tid >> 6;
  const int iq = lane & 7, jj = lane >> 3;
  const int j = wv * 8 + jj;

  f32x2 c22[8], a22[8], we2[8], aw2[8];
  const int pbase = j * 128 + iq * 16;
  #pragma unroll
  for (int p = 0; p < 8; ++p) {
    c22[p] = *(const f32x2*)(C2 + pbase + 2 * p);
    a22[p] = *(const f32x2*)(A2 + pbase + 2 * p);
    we2[p] = *(const f32x2*)(WE + pbase + 2 * p);
    aw2[p] = *(const f32x2*)(AW + pbase + 2 * p);
  }

  const int p0 = blockIdx.x << 9;        // 512 pairs per block
  uint4 hc0 = hbf[((size_t)p0 << 4) + iq * 2];
  uint4 hc1 = hbf[((size_t)p0 << 4) + iq * 2 + 1];

  for (int q = 0; q < 512; ++q) {
    const int p = p0 + q;
    const int pn = p0 + (q + 1 < 512 ? q + 1 : q);
    uint4 hn0 = hbf[((size_t)pn << 4) + iq * 2];
    uint4 hn1 = hbf[((size_t)pn << 4) + iq * 2 + 1];

    f32x2 hv[8];
    hv[0].x = bl16(hc0.x); hv[0].y = bh16(hc0.x);
    hv[1].x = bl16(hc0.y); hv[1].y = bh16(hc0.y);
    hv[2].x = bl16(hc0.z); hv[2].y = bh16(hc0.z);
    hv[3].x = bl16(hc0.w); hv[3].y = bh16(hc0.w);
    hv[4].x = bl16(hc1.x); hv[4].y = bh16(hc1.x);
    hv[5].x = bl16(hc1.y); hv[5].y = bh16(hc1.y);
    hv[6].x = bl16(hc1.z); hv[6].y = bh16(hc1.z);
    hv[7].x = bl16(hc1.w); hv[7].y = bh16(hc1.w);

    f32x2 an2 = {0.f, 0.f}, ad2 = {0.f, 0.f};
    #pragma unroll
    for (int p8 = 0; p8 < 8; ++p8)
      sigacc2(c22[p8], a22[p8], we2[p8], aw2[p8], hv[p8], an2, ad2);

    float an = red8(an2.x + an2.y);
    float ad = red8(ad2.x + ad2.y);
    if (iq == 0) ndg[((size_t)p << 7) + j] = pk2(an, ad);
    hc0 = hn0; hc1 = hn1;
  }
}

// ---------------- stage C: sequential LTC scan — packed math, stride-36 v, DPP reduce ----------------
__global__ __launch_bounds__(1024, 4) void ltc_scan(
    const float* __restrict__ C2, const float* __restrict__ A2,
    const float* __restrict__ WE, const float* __restrict__ AW,
    const float* __restrict__ vecs, const unsigned* __restrict__ ndg,
    const float* __restrict__ ow, const float* __restrict__ ob,
    const float* __restrict__ lng, const float* __restrict__ lnb,
    const float* __restrict__ hW, const float* __restrict__ hb,
    float* __restrict__ out)
{
  __shared__ float vbuf[2][8 * 36];
  __shared__ float ov[128], lnv[128], mv[2];

  const int tid = threadIdx.x;
  const int lane = tid & 63, wv = tid >> 6;
  const int iq = lane & 7, jj = lane >> 3;
  const int j = wv * 8 + jj;
  const int b = blockIdx.x;
  const int vpos_j = ((j >> 4) * 36) + (j & 15);

  f32x2 c22[8], a22[8], we2[8], aw2[8];
  const int pbase = j * 128 + iq * 16;
  #pragma unroll
  for (int p = 0; p < 8; ++p) {
    c22[p] = *(const f32x2*)(C2 + pbase + 2 * p);
    a22[p] = *(const f32x2*)(A2 + pbase + 2 * p);
    we2[p] = *(const f32x2*)(WE + pbase + 2 * p);
    aw2[p] = *(const f32x2*)(AW + pbase + 2 * p);
  }
  const float cmtj = vecs[j];
  const float gdj  = vecs[128 + j];
  const float gnj  = vecs[256 + j];
  float vj = 0.f;
  if (tid < 128) vbuf[0][((tid >> 4) * 36) + (tid & 15)] = 0.f;
  __syncthreads();

  const size_t ndbase = ((size_t)b << 17) + j;   // b*1024*128 + j
  unsigned ndc = ndg[ndbase];                    // t = 0 sensory terms
  for (int t = 0; t < 1024; ++t) {
    const int tn = (t + 1 < 1024) ? t + 1 : 1023;
    unsigned ndn = ndg[ndbase + ((size_t)tn << 7)];   // prefetch next t
    const float snum = bl16(ndc), sden = bh16(ndc);
    #pragma unroll
    for (int u = 0; u < 4; ++u) {
      const float* vc = vbuf[u & 1] + iq * 36;
      f32x2 an2 = {0.f, 0.f}, ad2 = {0.f, 0.f};
      #pragma unroll
      for (int c = 0; c < 4; ++c) {
        float4 vv = *(const float4*)(vc + 4 * c);
        f32x2 vA; vA.x = vv.x; vA.y = vv.y;
        f32x2 vB; vB.x = vv.z; vB.y = vv.w;
        sigacc2(c22[2 * c],     a22[2 * c],     we2[2 * c],     aw2[2 * c],     vA, an2, ad2);
        sigacc2(c22[2 * c + 1], a22[2 * c + 1], we2[2 * c + 1], aw2[2 * c + 1], vB, an2, ad2);
      }
      float an = red8(an2.x + an2.y);
      float ad = red8(ad2.x + ad2.y);
      // all lanes compute vnew for their j (identical across iq dups) -> vj stays in reg
      float num = an + snum;
      float den = ad + sden;
      float vnew = (fmaf(cmtj, vj, gnj) + num) *
                   __builtin_amdgcn_rcpf(cmtj + gdj + den + 1e-8f);
      if (iq == 0) vbuf[(u & 1) ^ 1][vpos_j] = vnew;
      vj = vnew;
      __syncthreads();
    }
    ndc = ndn;
  }

  // epilogue: out affine -> layernorm -> head matmul (final v is in vbuf[0], padded layout)
  if (tid < 128)
    ov[tid] = fmaf(vbuf[0][((tid >> 4) * 36) + (tid & 15)], ow[tid], ob[tid]);
  __syncthreads();
  if (tid < 64) {
    float a = ov[tid], c = ov[tid + 64];
    float s = a + c, s2 = fmaf(a, a, c * c);
    #pragma unroll
    for (int m = 1; m < 64; m <<= 1) {
      s += __shfl_xor(s, m, 64);
      s2 += __shfl_xor(s2, m, 64);
    }
    if (tid == 0) {
      float mean = s * (1.f / 128.f);
      float var = s2 * (1.f / 128.f) - mean * mean;
      mv[0] = mean;
      mv[1] = rsqrtf(var + 1e-5f);
    }
  }
  __syncthreads();
  if (tid < 128) lnv[tid] = fmaf((ov[tid] - mv[0]) * mv[1], lng[tid], lnb[tid]);
  __syncthreads();
  if (tid < 15) {
    float acc = hb[tid];
    const float* wr = hW + tid * 128;
    #pragma unroll
    for (int k = 0; k < 128; k += 4) {
      float4 wvv = *(const float4*)(wr + k);
      acc = fmaf(wvv.x, lnv[k], acc);
      acc = fmaf(wvv.y, lnv[k + 1], acc);
      acc = fmaf(wvv.z, lnv[k + 2], acc);
      acc = fmaf(wvv.w, lnv[k + 3], acc);
    }
    out[b * 15 + tid] = acc;
  }
}

// ---------------- launch ----------------
extern "C" void kernel_launch(void* const* d_in, const int* in_sizes, int n_in,
                              void* d_out, int out_size, void* d_ws, size_t ws_size,
                              hipStream_t stream) {
  const float* x      = (const float*)d_in[0];
  const float* pre_W  = (const float*)d_in[1];
  const float* pre_b  = (const float*)d_in[2];
  const float* plg    = (const float*)d_in[3];
  const float* plb    = (const float*)d_in[4];
  const float* gleak  = (const float*)d_in[5];
  const float* vleak  = (const float*)d_in[6];
  const float* cm     = (const float*)d_in[7];
  const float* sigma  = (const float*)d_in[8];
  const float* mu     = (const float*)d_in[9];
  const float* w      = (const float*)d_in[10];
  const float* erev   = (const float*)d_in[11];
  const float* ss     = (const float*)d_in[12];
  const float* smu    = (const float*)d_in[13];
  const float* sw     = (const float*)d_in[14];
  const float* serev  = (const float*)d_in[15];
  const float* iw     = (const float*)d_in[16];
  const float* ib     = (const float*)d_in[17];
  const float* ow     = (const float*)d_in[18];
  const float* ob     = (const float*)d_in[19];
  const float* lng    = (const float*)d_in[20];
  const float* lnb    = (const float*)d_in[21];
  const float* hW     = (const float*)d_in[22];
  const float* hb     = (const float*)d_in[23];
  float* out = (float*)d_out;

  char* ws = (char*)d_ws;
  float* C2r = (float*)(ws + 0 * 65536);
  float* A2r = (float*)(ws + 1 * 65536);
  float* WEr = (float*)(ws + 2 * 65536);
  float* AWr = (float*)(ws + 3 * 65536);
  float* C2s = (float*)(ws + 4 * 65536);
  float* A2s = (float*)(ws + 5 * 65536);
  float* WEs = (float*)(ws + 6 * 65536);
  float* AWs = (float*)(ws + 7 * 65536);
  float* vecs   = (float*)(ws + 8 * 65536);               // 1.5 KB
  uint4* hbf    = (uint4*)(ws + 1048576);                 // 32 MB (bf16 h_ln)
  unsigned* ndg = (unsigned*)(ws + 1048576 + 33554432);   // 64 MB (bf16 num|den)

  prep_kernel<<<129, 256, 0, stream>>>(sigma, mu, w, erev, ss, smu, sw, serev,
                                       iw, ib, gleak, vleak, cm,
                                       C2r, A2r, WEr, AWr, C2s, A2s, WEs, AWs, vecs);
  stage_a<<<4096, 256, 84480, stream>>>(x, pre_W, pre_b, plg, plb, hbf);
  sensory_kernel<<<256, 1024, 0, stream>>>(C2s, A2s, WEs, AWs, hbf, ndg);
  ltc_scan<<<128, 1024, 0, stream>>>(C2r, A2r, WEr, AWr, vecs, ndg,
                                     ow, ob, lng, lnb, hW, hb, out);
}